// Round 1
// 1653.761 us; speedup vs baseline: 1.1775x; 1.1775x over previous
//
#include <hip/hip_runtime.h>

// ---------------------------------------------------------------------------
// NaryCompUSchema: embed -> 3x masked LSTM (last hidden) -> segment_sum -> BPR
//   P[v, 0:1024]   = embed[v] @ col_W_ih^T + (col_b_ih + col_b_hh)   (bf16)
//   P[v,1024:2048] = embed[v] @ row_W_ih^T + (row_b_ih + row_b_hh)
//   Recurrence: gates^T = W_hh * h^T via mfma_f32_16x16x32_bf16.
// This revision attacks the LSTM dependency chain:
//   - W_hh pre-packed in per-wave fragment order (contiguous 1KB frags)
//   - h double-buffered in LDS -> ONE barrier/step, lgkmcnt-only (no vmcnt
//     drain: global loads pipeline across timesteps)
//   - P-row gathers prefetched one step ahead (tokens two ahead)
//   - step split into two u-halves: acc 64 VGPRs, headroom for load staging
// ---------------------------------------------------------------------------

typedef __bf16 bf16x8 __attribute__((ext_vector_type(8)));
typedef float  fvec4  __attribute__((ext_vector_type(4)));

#define NSEN 4096
#define HIDN 256
#define EMBD 300
#define VOC  50000

// workspace layout (bytes)
#define OFF_P     0ULL            // ushort [50000][2048]
#define OFF_WCAT  204800000ULL    // ushort [2048][320]   (ih weights, K padded)
#define OFF_WHHC  206110720ULL    // ushort [262144]      (packed frag order)
#define OFF_WHHR  206635008ULL    // ushort [262144]      (packed frag order)
#define OFF_BIAS  207159296ULL    // float  [2048]
#define OFF_H     207167488ULL    // float  [3][4096][256]
#define OFF_SEG   219750400ULL    // float  [3][4096][256]
#define OFF_LOSS  232333312ULL    // float  [4096]

static __device__ __forceinline__ unsigned short f2bf(float x) {
    unsigned int u = __float_as_uint(x);
    unsigned int r = (u + 0x7fffu + ((u >> 16) & 1u)) >> 16;  // RNE
    return (unsigned short)r;
}
static __device__ __forceinline__ float bf2f(unsigned short b) {
    return __uint_as_float(((unsigned int)b) << 16);
}
static __device__ __forceinline__ float sigm(float x) { return 1.f / (1.f + __expf(-x)); }
static __device__ __forceinline__ float tanh_(float x) {
    float e = __expf(2.f * x);
    return 1.f - 2.f / (e + 1.f);   // stable at +-inf
}
static __device__ __forceinline__ fvec4 unpk(uint2 v) {
    fvec4 o;
    o[0] = __uint_as_float((v.x & 0xffffu) << 16);
    o[1] = __uint_as_float(v.x & 0xffff0000u);
    o[2] = __uint_as_float((v.y & 0xffffu) << 16);
    o[3] = __uint_as_float(v.y & 0xffff0000u);
    return o;
}

// Whh packed layout: frag L = (((wv*2+hf)*8+kt)*4+g)*2+uh, elem = L*512 + ln*8 + j
// lane ln holds Whh[row][col], row = g*256+wv*64+(hf*2+uh)*16+(ln&15),
//                              col = kt*32+(ln>>4)*8+j
static __device__ __forceinline__ int whh_src(int o) {
    int L  = o >> 9;
    int r9 = o & 511;
    int ln = r9 >> 3, j = r9 & 7;
    int uh = L & 1, g = (L >> 1) & 3, kt = (L >> 3) & 7;
    int hf = (L >> 6) & 1, wv = (L >> 7) & 3;
    int row = g * 256 + wv * 64 + (hf * 2 + uh) * 16 + (ln & 15);
    int col = kt * 32 + (ln >> 4) * 8 + j;
    return row * 256 + col;
}

// ---------------------------------------------------------------- prep: pack
__global__ void prep_kernel(
    const float* __restrict__ cWih, const float* __restrict__ rWih,
    const float* __restrict__ cWhh, const float* __restrict__ rWhh,
    const float* __restrict__ cbih, const float* __restrict__ cbhh,
    const float* __restrict__ rbih, const float* __restrict__ rbhh,
    unsigned short* __restrict__ Wcat, unsigned short* __restrict__ WhhC,
    unsigned short* __restrict__ WhhR, float* __restrict__ biascat)
{
    int idx = blockIdx.x * 256 + threadIdx.x;
    if (idx < 2048 * 320) {
        int n = idx / 320, k = idx - n * 320;
        float v = 0.f;
        if (k < EMBD) v = (n < 1024) ? cWih[n * EMBD + k] : rWih[(n - 1024) * EMBD + k];
        Wcat[idx] = f2bf(v);
        return;
    }
    idx -= 2048 * 320;
    if (idx < 262144) { WhhC[idx] = f2bf(cWhh[whh_src(idx)]); return; }
    idx -= 262144;
    if (idx < 262144) { WhhR[idx] = f2bf(rWhh[whh_src(idx)]); return; }
    idx -= 262144;
    if (idx < 2048)
        biascat[idx] = (idx < 1024) ? (cbih[idx] + cbhh[idx])
                                    : (rbih[idx - 1024] + rbhh[idx - 1024]);
}

// ------------------------------------------------------- P = embed @ Wcat^T
__global__ __launch_bounds__(256) void gemm_p_kernel(
    const float* __restrict__ A,          // embed [50000][300] fp32
    const unsigned short* __restrict__ Bw,// Wcat  [2048][320] bf16
    const float* __restrict__ bias,       // [2048]
    unsigned short* __restrict__ Pout)    // [50000][2048] bf16
{
    const int nb = blockIdx.x * 128;
    const int mb = blockIdx.y * 128;
    const int tid = threadIdx.x;
    const int wv = tid >> 6, ln = tid & 63, l15 = ln & 15, q = ln >> 4;
    const int wm = wv & 1, wn = wv >> 1;

    __shared__ __align__(16) unsigned short At[128][40]; // [m][k] bf16, pad->40

    fvec4 acc[4][4];
    #pragma unroll
    for (int a = 0; a < 4; ++a)
        #pragma unroll
        for (int b = 0; b < 4; ++b) acc[a][b] = (fvec4)0.f;

    for (int kt = 0; kt < 10; ++kt) {
        const int K0 = kt * 32;
        __syncthreads();
        {
            int tr = tid >> 3;   // 0..31
            int tc = tid & 7;    // float4 column
            #pragma unroll
            for (int p = 0; p < 4; ++p) {
                int rrow = tr + p * 32;
                int gr = mb + rrow;
                float4 v = make_float4(0.f, 0.f, 0.f, 0.f);
                if (gr < VOC && (K0 + tc * 4) < EMBD)
                    v = *(const float4*)(A + (size_t)gr * EMBD + K0 + tc * 4);
                ushort4 b;
                b.x = f2bf(v.x); b.y = f2bf(v.y); b.z = f2bf(v.z); b.w = f2bf(v.w);
                *(ushort4*)&At[rrow][tc * 4] = b;
            }
        }
        __syncthreads();
        bf16x8 bf_[4];
        #pragma unroll
        for (int ntt = 0; ntt < 4; ++ntt) {
            int n = nb + wn * 64 + ntt * 16 + l15;
            bf_[ntt] = *(const bf16x8*)(Bw + (size_t)n * 320 + K0 + q * 8);
        }
        #pragma unroll
        for (int mt = 0; mt < 4; ++mt) {
            bf16x8 af = *(const bf16x8*)&At[wm * 64 + mt * 16 + l15][q * 8];
            #pragma unroll
            for (int ntt = 0; ntt < 4; ++ntt)
                acc[mt][ntt] = __builtin_amdgcn_mfma_f32_16x16x32_bf16(
                    af, bf_[ntt], acc[mt][ntt], 0, 0, 0);
        }
    }
    float bv[4];
    #pragma unroll
    for (int ntt = 0; ntt < 4; ++ntt) bv[ntt] = bias[nb + wn * 64 + ntt * 16 + l15];
    #pragma unroll
    for (int mt = 0; mt < 4; ++mt) {
        #pragma unroll
        for (int r = 0; r < 4; ++r) {
            int m = mb + wm * 64 + mt * 16 + q * 4 + r;
            if (m < VOC) {
                size_t base = (size_t)m * 2048 + nb + wn * 64;
                #pragma unroll
                for (int ntt = 0; ntt < 4; ++ntt)
                    Pout[base + ntt * 16 + l15] = f2bf(acc[mt][ntt][r] + bv[ntt]);
            }
        }
    }
}

// ----------------------------------------------------------------- LSTMs
// grid 384: blocks [0,128) col, [128,256) row, [256,384) row_neg.
// Block: 32 seqs, 4 waves; wave wv owns hidden units [64wv,64wv+64).
// One asm barrier per step (lgkmcnt only); h double-buffered in LDS;
// P gathers prefetched one step ahead; Whh read as packed contiguous frags.
__global__ __launch_bounds__(256, 1) void lstm_kernel(
    const int* __restrict__ colTok, const int* __restrict__ rowTok, const int* __restrict__ negTok,
    const int* __restrict__ colLen, const int* __restrict__ rowLen, const int* __restrict__ negLen,
    const unsigned short* __restrict__ P,
    const unsigned short* __restrict__ WhhC, const unsigned short* __restrict__ WhhR,
    float* __restrict__ Hout)
{
    const int part = blockIdx.x >> 7;
    const int sb = blockIdx.x & 127;
    const int s0 = sb * 32;
    const int* tok = part == 0 ? colTok : (part == 1 ? rowTok : negTok);
    const int* len = part == 0 ? colLen : (part == 1 ? rowLen : negLen);
    const unsigned short* Whh = part == 0 ? WhhC : WhhR;
    const int T = part == 0 ? 64 : 16;
    const int pco = part == 0 ? 0 : 1024;
    float* Ho = Hout + (size_t)part * (NSEN * HIDN);

    const int tid = threadIdx.x;
    const int wv = tid >> 6, ln = tid & 63, l15 = ln & 15, q = ln >> 4;

    __shared__ __align__(16) unsigned short hbf[2][32][264]; // double-buffered h
    __shared__ int lenS[32];
    __shared__ int mlS;

    for (int i = tid; i < 2 * 32 * 264; i += 256) (&hbf[0][0][0])[i] = 0;
    if (tid < 32) lenS[tid] = len[s0 + tid];
    __syncthreads();
    if (tid == 0) { int m = 0; for (int i = 0; i < 32; ++i) m = max(m, lenS[i]); mlS = m; }
    __syncthreads();
    const int maxlen = mlS;
    const int len0 = lenS[l15], len1 = lenS[16 + l15];

    // per-wave contiguous packed-Whh stream base
    const unsigned short* wbase = Whh + (size_t)wv * 65536 + (size_t)ln * 8;

    float c[4][2][4];
    #pragma unroll
    for (int u = 0; u < 4; ++u)
        #pragma unroll
        for (int n = 0; n < 2; ++n)
            #pragma unroll
            for (int r = 0; r < 4; ++r) c[u][n][r] = 0.f;

    ushort4 hpk[4][2];   // frozen h (packed bf16) per (u, nt)
    #pragma unroll
    for (int u = 0; u < 4; ++u)
        #pragma unroll
        for (int n = 0; n < 2; ++n) hpk[u][n] = make_ushort4(0, 0, 0, 0);

    // ---- prologue: gather P for t=0, prefetch tokens for t=1
    uint2 pbuf[4][4][2];  // [g][u][nt]
    {
        int tk0 = tok[(s0 + l15) * T];
        int tk1 = tok[(s0 + 16 + l15) * T];
        const unsigned short* pr0 = P + (size_t)tk0 * 2048 + pco;
        const unsigned short* pr1 = P + (size_t)tk1 * 2048 + pco;
        #pragma unroll
        for (int g = 0; g < 4; ++g)
            #pragma unroll
            for (int u = 0; u < 4; ++u) {
                int e = g * 256 + wv * 64 + u * 16 + q * 4;
                pbuf[g][u][0] = *(const uint2*)(pr0 + e);
                pbuf[g][u][1] = *(const uint2*)(pr1 + e);
            }
    }
    int tkn0 = tok[(s0 + l15) * T + 1];        // T >= 16 so index 1 is valid
    int tkn1 = tok[(s0 + 16 + l15) * T + 1];

    for (int t = 0; t < maxlen; ++t) {
        const unsigned short (*hb)[264] = hbf[t & 1];
        unsigned short (*hw)[264] = hbf[(t + 1) & 1];

        #pragma unroll
        for (int hf = 0; hf < 2; ++hf) {
            // acc init from prefetched P rows (this half's u = hf*2 + uh)
            fvec4 acc[4][2][2];
            #pragma unroll
            for (int g = 0; g < 4; ++g)
                #pragma unroll
                for (int uh = 0; uh < 2; ++uh) {
                    acc[g][uh][0] = unpk(pbuf[g][hf * 2 + uh][0]);
                    acc[g][uh][1] = unpk(pbuf[g][hf * 2 + uh][1]);
                }

            if (hf == 1) {
                // pbuf fully consumed: issue next-step gathers (latency hides
                // under this half's MFMA + activation + barrier)
                const unsigned short* pr0 = P + (size_t)tkn0 * 2048 + pco;
                const unsigned short* pr1 = P + (size_t)tkn1 * 2048 + pco;
                #pragma unroll
                for (int g = 0; g < 4; ++g)
                    #pragma unroll
                    for (int u = 0; u < 4; ++u) {
                        int e = g * 256 + wv * 64 + u * 16 + q * 4;
                        pbuf[g][u][0] = *(const uint2*)(pr0 + e);
                        pbuf[g][u][1] = *(const uint2*)(pr1 + e);
                    }
                int t2 = (t + 2 < T) ? (t + 2) : (T - 1);
                tkn0 = tok[(s0 + l15) * T + t2];
                tkn1 = tok[(s0 + 16 + l15) * T + t2];
            }

            // gates += Whh_half * h^T  (contiguous packed frag stream)
            #pragma unroll
            for (int kt = 0; kt < 8; ++kt) {
                bf16x8 b0 = *(const bf16x8*)&hb[l15][kt * 32 + q * 8];
                bf16x8 b1 = *(const bf16x8*)&hb[16 + l15][kt * 32 + q * 8];
                const unsigned short* wp = wbase + (size_t)(hf * 8 + kt) * 4096;
                #pragma unroll
                for (int g = 0; g < 4; ++g) {
                    #pragma unroll
                    for (int uh = 0; uh < 2; ++uh) {
                        bf16x8 a = *(const bf16x8*)(wp + (size_t)(g * 2 + uh) * 512);
                        acc[g][uh][0] = __builtin_amdgcn_mfma_f32_16x16x32_bf16(a, b0, acc[g][uh][0], 0, 0, 0);
                        acc[g][uh][1] = __builtin_amdgcn_mfma_f32_16x16x32_bf16(a, b1, acc[g][uh][1], 0, 0, 0);
                    }
                }
            }

            // activation + packed h store (all lanes store: frozen lanes copy)
            #pragma unroll
            for (int uh = 0; uh < 2; ++uh) {
                const int u = hf * 2 + uh;
                #pragma unroll
                for (int nt = 0; nt < 2; ++nt) {
                    bool act = t < (nt ? len1 : len0);
                    if (act) {
                        float hr[4];
                        #pragma unroll
                        for (int r = 0; r < 4; ++r) {
                            float iv = acc[0][uh][nt][r];
                            float fv = acc[1][uh][nt][r];
                            float gv = acc[2][uh][nt][r];
                            float ov = acc[3][uh][nt][r];
                            float cn = sigm(fv) * c[u][nt][r] + sigm(iv) * tanh_(gv);
                            c[u][nt][r] = cn;
                            hr[r] = sigm(ov) * tanh_(cn);
                        }
                        hpk[u][nt] = make_ushort4(f2bf(hr[0]), f2bf(hr[1]),
                                                  f2bf(hr[2]), f2bf(hr[3]));
                    }
                    *(ushort4*)&hw[nt * 16 + l15][wv * 64 + u * 16 + q * 4] = hpk[u][nt];
                }
            }
        }
        // ONE barrier per step: wait only LDS ops; global loads stay in flight
        asm volatile("s_waitcnt lgkmcnt(0)\n\ts_barrier" ::: "memory");
    }

    for (int i = tid; i < 32 * HIDN; i += 256) {
        int sq = i >> 8, hd = i & 255;
        Ho[(size_t)(s0 + sq) * HIDN + hd] = bf2f(hbf[maxlen & 1][sq][hd]);
    }
}

// ------------------------------------------------------------ segment sum
__global__ void scatter_kernel(const float* __restrict__ Hout,
                               const int* __restrict__ crefs, const int* __restrict__ rrefs,
                               const int* __restrict__ nrefs, float* __restrict__ seg)
{
    int idx = blockIdx.x * 256 + threadIdx.x;       // < 3 * 2^20
    int which = idx >> 20;
    int rem = idx & 1048575;
    int s = rem >> 8, hd = rem & 255;
    const int* refs = which == 0 ? crefs : (which == 1 ? rrefs : nrefs);
    int rf = refs[s];
    atomicAdd(&seg[(size_t)which * 1048576 + (size_t)rf * 256 + hd], Hout[idx]);
}

// ------------------------------------------------------------------ loss
__global__ void loss_kernel(const float* __restrict__ seg, float* __restrict__ part)
{
    int d = blockIdx.x, tid = threadIdx.x;
    const float* sc = seg + (size_t)d * 256;
    const float* sr = seg + 1048576 + (size_t)d * 256;
    const float* sn = seg + 2097152 + (size_t)d * 256;
    float a = sc[tid];
    float p = a * sr[tid];
    float n = a * sn[tid];
    for (int off = 32; off; off >>= 1) { p += __shfl_down(p, off); n += __shfl_down(n, off); }
    __shared__ float rp[4], rn[4];
    if ((tid & 63) == 0) { rp[tid >> 6] = p; rn[tid >> 6] = n; }
    __syncthreads();
    if (tid == 0) {
        float Ps = rp[0] + rp[1] + rp[2] + rp[3];
        float Ns = rn[0] + rn[1] + rn[2] + rn[3];
        float x = Ps - Ns;
        part[d] = fmaxf(-x, 0.f) + log1pf(expf(-fabsf(x)));  // softplus(-x)
    }
}

__global__ void reduce_kernel(const float* __restrict__ part, float* __restrict__ out)
{
    int tid = threadIdx.x;
    float s = 0.f;
    for (int i = tid; i < 4096; i += 256) s += part[i];
    for (int off = 32; off; off >>= 1) s += __shfl_down(s, off);
    __shared__ float r[4];
    if ((tid & 63) == 0) r[tid >> 6] = s;
    __syncthreads();
    if (tid == 0) out[0] = r[0] + r[1] + r[2] + r[3];
}

// ---------------------------------------------------------------------------
extern "C" void kernel_launch(void* const* d_in, const int* in_sizes, int n_in,
                              void* d_out, int out_size, void* d_ws, size_t ws_size,
                              hipStream_t stream)
{
    const int*   col      = (const int*)d_in[0];
    const int*   row      = (const int*)d_in[1];
    const int*   rneg     = (const int*)d_in[2];
    const int*   col_lens = (const int*)d_in[3];
    const int*   row_lens = (const int*)d_in[4];
    const int*   rng_lens = (const int*)d_in[5];
    const int*   col_refs = (const int*)d_in[6];
    const int*   row_refs = (const int*)d_in[7];
    const int*   rng_refs = (const int*)d_in[8];
    const float* embed    = (const float*)d_in[9];
    const float* cWih     = (const float*)d_in[10];
    const float* cWhh     = (const float*)d_in[11];
    const float* cbih     = (const float*)d_in[12];
    const float* cbhh     = (const float*)d_in[13];
    const float* rWih     = (const float*)d_in[14];
    const float* rWhh     = (const float*)d_in[15];
    const float* rbih     = (const float*)d_in[16];
    const float* rbhh     = (const float*)d_in[17];

    char* ws = (char*)d_ws;
    unsigned short* P    = (unsigned short*)(ws + OFF_P);
    unsigned short* Wcat = (unsigned short*)(ws + OFF_WCAT);
    unsigned short* WhhC = (unsigned short*)(ws + OFF_WHHC);
    unsigned short* WhhR = (unsigned short*)(ws + OFF_WHHR);
    float* biascat = (float*)(ws + OFF_BIAS);
    float* Hbuf    = (float*)(ws + OFF_H);
    float* seg     = (float*)(ws + OFF_SEG);
    float* lpart   = (float*)(ws + OFF_LOSS);

    hipMemsetAsync(seg, 0, 3 * 4096 * 256 * sizeof(float), stream);

    prep_kernel<<<4616, 256, 0, stream>>>(cWih, rWih, cWhh, rWhh,
                                          cbih, cbhh, rbih, rbhh,
                                          Wcat, WhhC, WhhR, biascat);
    gemm_p_kernel<<<dim3(16, 391), 256, 0, stream>>>(embed, Wcat, biascat, P);
    lstm_kernel<<<384, 256, 0, stream>>>(col, row, rneg,
                                         col_lens, row_lens, rng_lens,
                                         P, WhhC, WhhR, Hbuf);
    scatter_kernel<<<12288, 256, 0, stream>>>(Hbuf, col_refs, row_refs, rng_refs, seg);
    loss_kernel<<<4096, 256, 0, stream>>>(seg, lpart);
    reduce_kernel<<<1, 256, 0, stream>>>(lpart, (float*)d_out);
}